// Round 1
// baseline (205.430 us; speedup 1.0000x reference)
//
#include <hip/hip_runtime.h>
#include <stdint.h>

typedef unsigned short u16;
typedef unsigned int u32;
typedef unsigned long long u64;

typedef __attribute__((ext_vector_type(8))) short bf16x8;
typedef __attribute__((ext_vector_type(4))) float f32x4;

// ---------------- workspace layout (bytes) ----------------
#define OFF_SBITS 0u
#define SBITS_BYTES (2048u * 128u * 32u)            // 8 MiB: u64[2048][128][4]
#define OFF_WHI  (SBITS_BYTES)                       // bf16[256][256]
#define OFF_WLO  (OFF_WHI  + 131072u)
#define OFF_WLO2 (OFF_WLO  + 131072u)
#define OFF_C0   (OFF_WLO2 + 131072u)                // float4[256]: w0,w1,w2,inv
#define OFF_C1   (OFF_C0   + 4096u)                  // float4[256]: cb,mean,beta,0

__device__ __forceinline__ u16 f32_to_bf16_rn(float f) {
    u32 u = __float_as_uint(f);
    u32 r = (u + 0x7FFFu + ((u >> 16) & 1u)) >> 16;
    return (u16)r;
}
__device__ __forceinline__ float bf16_to_f32(u16 h) {
    return __uint_as_float(((u32)h) << 16);
}

// ---------------- kernel 1: prep (W 3-way bf16 split + BN-folded coefs) ----
__global__ __launch_bounds__(256) void prep_kernel(
    const float* __restrict__ conv_w, const float* __restrict__ conv_b,
    const float* __restrict__ gamma,  const float* __restrict__ beta,
    const float* __restrict__ mean,   const float* __restrict__ var,
    const float* __restrict__ lin_w,  uint8_t* __restrict__ ws) {
    int tid = threadIdx.x;
    int blk = blockIdx.x;
    if (blk < 256) {
        int j = blk;
        float w = lin_w[j * 256 + tid];
        u16 hi = f32_to_bf16_rn(w);
        float r1 = w - bf16_to_f32(hi);
        u16 lo = f32_to_bf16_rn(r1);
        float r2 = r1 - bf16_to_f32(lo);
        u16 lo2 = f32_to_bf16_rn(r2);
        ((u16*)(ws + OFF_WHI ))[j * 256 + tid] = hi;
        ((u16*)(ws + OFF_WLO ))[j * 256 + tid] = lo;
        ((u16*)(ws + OFF_WLO2))[j * 256 + tid] = lo2;
    } else {
        int h = tid;
        float inv = gamma[h] / sqrtf(var[h] + 1e-5f);
        float4 c0 = make_float4(conv_w[h * 3 + 0], conv_w[h * 3 + 1],
                                conv_w[h * 3 + 2], inv);
        float4 c1 = make_float4(conv_b[h], mean[h], beta[h], 0.f);
        ((float4*)(ws + OFF_C0))[h] = c0;
        ((float4*)(ws + OFF_C1))[h] = c1;
    }
}

// ---------------- kernel 2: encoder (conv+BN+LIF over h, bit-pack spikes) --
// thread <-> position p: c = p&31, l = (p>>5)&127, b = p>>12  (x reads coalesced)
__global__ __launch_bounds__(256) void encoder_kernel(
    const float* __restrict__ x,
    const float4* __restrict__ c0, const float4* __restrict__ c1,
    u64* __restrict__ sbits) {
    int p = blockIdx.x * 256 + threadIdx.x;       // 0..262143
    int c = p & 31;
    int l = (p >> 5) & 127;
    int b = p >> 12;
    int xbase = b * 4096 + l * 32 + c;
    float xb = x[xbase];
    float xa = (l > 0)   ? x[xbase - 32] : 0.f;
    float xc = (l < 127) ? x[xbase + 32] : 0.f;
    int n = b * 32 + c;
    u64* dst = sbits + ((size_t)n * 128 + (size_t)l) * 4;

    float v = 0.f;
    u64 cur = 0ull;
    #pragma unroll 8
    for (int h = 0; h < 256; ++h) {
        float4 a = c0[h];            // uniform -> s_load
        float4 d = c1[h];
        float conv = a.x * xa + a.y * xb + a.z * xc;
        float e = ((conv + d.x) - d.y) * a.w + d.z;   // ((enc+cb)-mean)*inv+beta
        v = v + (e - v) * 0.5f;                        // tau = 2
        bool s = (v >= 1.0f);
        cur |= ((u64)(s ? 1u : 0u)) << (h & 63);
        if ((h & 63) == 63) { dst[h >> 6] = cur; cur = 0ull; }
        v = s ? 0.f : v;                               // hard reset
    }
}

// ---------------- kernel 3: GEMM (binary A via bitmask, 3-split W) + scan --
// block = sequence n (2048 blocks). tile 128(t) x 256(j), 4 waves x [128x64].
// LDS: [0,4096)   A bitmask  (128 rows x 32 B)
//      [4096,64K) B tiles: 3 splits x 256 j x 40 u16 (80 B padded rows)
// epilogue reuse: Zbuf float[32][258]
#define BROW 40

__global__ __launch_bounds__(256, 2) void gemm_scan_kernel(
    const u64* __restrict__ sbits,
    const u16* __restrict__ whi, const u16* __restrict__ wlo,
    const u16* __restrict__ wlo2,
    const float* __restrict__ lin_b,
    float* __restrict__ out) {
    __shared__ __align__(16) uint8_t smem[65536];
    uint8_t* Abytes = smem;
    u16*     Blds   = (u16*)(smem + 4096);
    float*   Zbuf   = (float*)smem;

    int tid  = threadIdx.x;
    int n    = blockIdx.x;
    int lane = tid & 63;
    int w    = tid >> 6;
    int l15  = lane & 15;
    int quad = lane >> 4;

    // stage A bits: 4 KB
    {
        const uint4* src = (const uint4*)(sbits + (size_t)n * 512);
        ((uint4*)smem)[tid] = src[tid];
    }

    f32x4 acc[8][4];
    #pragma unroll
    for (int mf = 0; mf < 8; ++mf)
        #pragma unroll
        for (int nf = 0; nf < 4; ++nf) {
            f32x4 z = {0.f, 0.f, 0.f, 0.f};
            acc[mf][nf] = z;
        }

    for (int kc = 0; kc < 8; ++kc) {
        __syncthreads();
        // stage B chunk: 3 splits x 32 k x 256 j (48 KB), 12 x 16B per thread
        #pragma unroll
        for (int ii = 0; ii < 12; ++ii) {
            int cid = tid + 256 * ii;          // 0..3071
            int s   = cid >> 10;               // uniform per ii
            int rem = cid & 1023;
            int j   = rem >> 2;
            int q4  = rem & 3;
            const u16* wsrc = (s == 0) ? whi : (s == 1) ? wlo : wlo2;
            uint4 vv = *(const uint4*)(wsrc + (size_t)j * 256 + kc * 32 + q4 * 8);
            *(uint4*)(Blds + s * 10240 + j * BROW + q4 * 8) = vv;
        }
        __syncthreads();

        // A fragments from bitmask: byte (kc*4+quad) of row (mf*16+l15)
        bf16x8 afr[8];
        #pragma unroll
        for (int mf = 0; mf < 8; ++mf) {
            int row = mf * 16 + l15;
            u32 byte = Abytes[row * 32 + kc * 4 + quad];
            bf16x8 a;
            #pragma unroll
            for (int jj = 0; jj < 8; ++jj)
                a[jj] = (short)(((byte >> jj) & 1u) ? 0x3F80 : 0);
            afr[mf] = a;
        }
        #pragma unroll
        for (int s = 0; s < 3; ++s)
            #pragma unroll
            for (int nf = 0; nf < 4; ++nf) {
                bf16x8 bfr = *(const bf16x8*)(Blds + s * 10240 +
                                              (nf * 16 + l15) * BROW + quad * 8);
                #pragma unroll
                for (int mf = 0; mf < 8; ++mf)
                    acc[mf][nf] = __builtin_amdgcn_mfma_f32_16x16x32_bf16(
                        afr[mf], bfr, acc[mf][nf], 0, 0, 0);
            }
    }

    // ---- epilogue: LDS transpose (4 phases x 32 t) + LIF scan over t ----
    float bias = lin_b[tid];                   // j = tid
    float v = 0.f, sOut = 0.f;
    for (int ph = 0; ph < 4; ++ph) {
        __syncthreads();
        #pragma unroll
        for (int mm = 0; mm < 2; ++mm) {
            int mf = ph * 2 + mm;
            #pragma unroll
            for (int nf = 0; nf < 4; ++nf)
                #pragma unroll
                for (int r = 0; r < 4; ++r) {
                    int tl = mm * 16 + quad * 4 + r;           // 0..31
                    int jj = w * 64 + nf * 16 + l15;           // 0..255
                    Zbuf[tl * 258 + jj] = acc[mf][nf][r];
                }
        }
        __syncthreads();
        for (int tl = 0; tl < 32; ++tl) {
            float z = Zbuf[tl * 258 + tid] + bias;
            v = v + (z - v) * 0.5f;
            bool s = (v >= 1.0f);
            if (ph == 3 && tl == 31) sOut = s ? 1.f : 0.f;
            v = s ? 0.f : v;
        }
    }
    out[(size_t)n * 256 + tid]           = sOut;   // (64,1,8192) flat
    out[524288u + (size_t)n * 256 + tid] = sOut;   // (64,8192) flat (identical)
}

// ---------------- launcher ----------------
extern "C" void kernel_launch(void* const* d_in, const int* in_sizes, int n_in,
                              void* d_out, int out_size, void* d_ws, size_t ws_size,
                              hipStream_t stream) {
    const float* x      = (const float*)d_in[0];
    const float* conv_w = (const float*)d_in[1];
    const float* conv_b = (const float*)d_in[2];
    const float* gamma  = (const float*)d_in[3];
    const float* beta   = (const float*)d_in[4];
    const float* mean   = (const float*)d_in[5];
    const float* var    = (const float*)d_in[6];
    const float* lin_w  = (const float*)d_in[7];
    const float* lin_b  = (const float*)d_in[8];
    uint8_t* ws = (uint8_t*)d_ws;
    float* out = (float*)d_out;

    hipLaunchKernelGGL(prep_kernel, dim3(257), dim3(256), 0, stream,
                       conv_w, conv_b, gamma, beta, mean, var, lin_w, ws);
    hipLaunchKernelGGL(encoder_kernel, dim3(1024), dim3(256), 0, stream,
                       x, (const float4*)(ws + OFF_C0), (const float4*)(ws + OFF_C1),
                       (u64*)(ws + OFF_SBITS));
    hipLaunchKernelGGL(gemm_scan_kernel, dim3(2048), dim3(256), 0, stream,
                       (const u64*)(ws + OFF_SBITS),
                       (const u16*)(ws + OFF_WHI), (const u16*)(ws + OFF_WLO),
                       (const u16*)(ws + OFF_WLO2), lin_b, out);
}

// Round 2
// 173.561 us; speedup vs baseline: 1.1836x; 1.1836x over previous
//
#include <hip/hip_runtime.h>
#include <stdint.h>

typedef unsigned short u16;
typedef unsigned int u32;
typedef unsigned long long u64;

typedef _Float16 f16x8 __attribute__((ext_vector_type(8)));
typedef __attribute__((ext_vector_type(4))) float f32x4;

// ---------------- workspace layout (bytes) ----------------
#define OFF_SBITS 0u
#define SBITS_BYTES (2048u * 128u * 32u)             // 8 MiB: u64[2048][128][4]
#define OFF_WSWZ (SBITS_BYTES)                       // fp16 2-split, swizzled:
                                                     // [(s*8+kc)*1024 + j*4 + q4] x uint4
#define WSWZ_BYTES (2u * 8u * 1024u * 16u)           // 256 KiB
#define OFF_C0   (OFF_WSWZ + WSWZ_BYTES)             // float4[256]: w0,w1,w2,inv
#define OFF_C1   (OFF_C0   + 4096u)                  // float4[256]: cb,mean,beta,0

#define WSCALE 2048.0f
#define INV_WSCALE (1.0f / 2048.0f)

// ---------------- kernel 1: prep (W 2-way fp16 split, swizzled) ----
__global__ __launch_bounds__(256) void prep_kernel(
    const float* __restrict__ conv_w, const float* __restrict__ conv_b,
    const float* __restrict__ gamma,  const float* __restrict__ beta,
    const float* __restrict__ mean,   const float* __restrict__ var,
    const float* __restrict__ lin_w,  uint8_t* __restrict__ ws) {
    int tid = threadIdx.x;
    int blk = blockIdx.x;
    if (blk < 256) {
        int j = blk;
        int k = tid;
        float wsc = lin_w[j * 256 + k] * WSCALE;     // exact (x 2^11)
        _Float16 hi = (_Float16)wsc;                 // RN
        float r = wsc - (float)hi;
        _Float16 lo = (_Float16)r;
        union { _Float16 h; u16 u; } ch, cl;
        ch.h = hi; cl.h = lo;
        int kc = k >> 5, q4 = (k >> 3) & 3, k7 = k & 7;
        u16* whw = (u16*)(ws + OFF_WSWZ);
        size_t p0 = ((size_t)(0 * 8 + kc) * 1024 + j * 4 + q4) * 8 + k7;
        size_t p1 = ((size_t)(1 * 8 + kc) * 1024 + j * 4 + q4) * 8 + k7;
        whw[p0] = ch.u;
        whw[p1] = cl.u;
    } else {
        int h = tid;
        float inv = gamma[h] / sqrtf(var[h] + 1e-5f);
        float4 c0 = make_float4(conv_w[h * 3 + 0], conv_w[h * 3 + 1],
                                conv_w[h * 3 + 2], inv);
        float4 c1 = make_float4(conv_b[h], mean[h], beta[h], 0.f);
        ((float4*)(ws + OFF_C0))[h] = c0;
        ((float4*)(ws + OFF_C1))[h] = c1;
    }
}

// ---------------- kernel 2: encoder (conv+BN+LIF over h, bit-pack spikes) --
// UNCHANGED numerics vs round 1 (passed). thread p: c=p&31, l=(p>>5)&127, b=p>>12
__global__ __launch_bounds__(256) void encoder_kernel(
    const float* __restrict__ x,
    const float4* __restrict__ c0, const float4* __restrict__ c1,
    u64* __restrict__ sbits) {
    int p = blockIdx.x * 256 + threadIdx.x;       // 0..262143
    int c = p & 31;
    int l = (p >> 5) & 127;
    int b = p >> 12;
    int xbase = b * 4096 + l * 32 + c;
    float xb = x[xbase];
    float xa = (l > 0)   ? x[xbase - 32] : 0.f;
    float xc = (l < 127) ? x[xbase + 32] : 0.f;
    int n = b * 32 + c;
    u64* dst = sbits + ((size_t)n * 128 + (size_t)l) * 4;

    float v = 0.f;
    u64 cur = 0ull;
    #pragma unroll 8
    for (int h = 0; h < 256; ++h) {
        float4 a = c0[h];            // uniform -> s_load
        float4 d = c1[h];
        float conv = a.x * xa + a.y * xb + a.z * xc;
        float e = ((conv + d.x) - d.y) * a.w + d.z;
        v = v + (e - v) * 0.5f;
        bool s = (v >= 1.0f);
        cur |= ((u64)(s ? 1u : 0u)) << (h & 63);
        if ((h & 63) == 63) { dst[h >> 6] = cur; cur = 0ull; }
        v = s ? 0.f : v;
    }
}

// ---------------- kernel 3: GEMM (binary A bits, 2-split fp16 W) + scan ----
// block = sequence n (2048 blocks). tile 128(t) x 256(j), 4 waves x [128x64].
// LDS: [0,6144)        A words: 128 rows x 12 dwords (8 data + 4 pad)
//      [6144,47104)    B: 2 splits x 256 j x 40 u16 (80 B padded rows)
// epilogue reuse: Zbuf float[32][258] = 33024 B
#define BROW 40
#define AROW 12

__global__ __launch_bounds__(256, 2) void gemm_scan_kernel(
    const u64* __restrict__ sbits,
    const uint4* __restrict__ wswz,
    const float* __restrict__ lin_b,
    float* __restrict__ out) {
    __shared__ __align__(16) uint8_t smem[47104];
    u32* Awords = (u32*)smem;
    u16* Blds   = (u16*)(smem + 6144);
    float* Zbuf = (float*)smem;

    int tid  = threadIdx.x;
    int n    = blockIdx.x;
    int lane = tid & 63;
    int w    = tid >> 6;
    int l15  = lane & 15;
    int quad = lane >> 4;

    // stage A bits: 4 KB data into 48 B-padded rows (bank-friendly b32 reads)
    {
        const uint4* src = (const uint4*)(sbits + (size_t)n * 512);
        uint4 v = src[tid];
        *(uint4*)(Awords + (tid >> 1) * AROW + (tid & 1) * 4) = v;
    }

    f32x4 acc[8][4];
    #pragma unroll
    for (int mf = 0; mf < 8; ++mf)
        #pragma unroll
        for (int nf = 0; nf < 4; ++nf) {
            f32x4 z = {0.f, 0.f, 0.f, 0.f};
            acc[mf][nf] = z;
        }

    for (int kc = 0; kc < 8; ++kc) {
        __syncthreads();
        // stage B chunk: 2 splits x 32 k x 256 j = 32 KB, linear copy 8x16B/thread
        #pragma unroll
        for (int ii = 0; ii < 8; ++ii) {
            int cid = tid + 256 * ii;          // 0..2047
            int s   = cid >> 10;
            int rem = cid & 1023;
            uint4 vv = wswz[(size_t)(s * 8 + kc) * 1024 + rem];
            int j  = rem >> 2;
            int q4 = rem & 3;
            *(uint4*)(Blds + s * 10240 + j * BROW + q4 * 8) = vv;
        }
        __syncthreads();

        // A fragments from bitmask: dword kc of row (mf*16+l15), byte quad
        f16x8 afr[8];
        #pragma unroll
        for (int mf = 0; mf < 8; ++mf) {
            u32 word = Awords[(mf * 16 + l15) * AROW + kc];
            u32 b = (word >> (quad * 8)) & 0xFFu;
            u32 s1 = b | (b << 15);
            union { u32 u[4]; f16x8 v; } cv;
            cv.u[0] = ((s1     ) & 0x00010001u) * 0x3C00u;
            cv.u[1] = ((s1 >> 2) & 0x00010001u) * 0x3C00u;
            cv.u[2] = ((s1 >> 4) & 0x00010001u) * 0x3C00u;
            cv.u[3] = ((s1 >> 6) & 0x00010001u) * 0x3C00u;
            afr[mf] = cv.v;
        }
        #pragma unroll
        for (int s = 0; s < 2; ++s)
            #pragma unroll
            for (int nf = 0; nf < 4; ++nf) {
                f16x8 bfr = *(const f16x8*)(Blds + s * 10240 +
                                            (w * 64 + nf * 16 + l15) * BROW + quad * 8);
                #pragma unroll
                for (int mf = 0; mf < 8; ++mf)
                    acc[mf][nf] = __builtin_amdgcn_mfma_f32_16x16x32_f16(
                        afr[mf], bfr, acc[mf][nf], 0, 0, 0);
            }
    }

    // ---- epilogue: LDS transpose (4 phases x 32 t) + LIF scan over t ----
    float bias = lin_b[tid];                   // j = tid
    float v = 0.f, sOut = 0.f;
    for (int ph = 0; ph < 4; ++ph) {
        __syncthreads();
        #pragma unroll
        for (int mm = 0; mm < 2; ++mm) {
            int mf = ph * 2 + mm;
            #pragma unroll
            for (int nf = 0; nf < 4; ++nf)
                #pragma unroll
                for (int r = 0; r < 4; ++r) {
                    int tl = mm * 16 + quad * 4 + r;           // 0..31
                    int jj = w * 64 + nf * 16 + l15;           // 0..255
                    Zbuf[tl * 258 + jj] = acc[mf][nf][r];
                }
        }
        __syncthreads();
        for (int tl = 0; tl < 32; ++tl) {
            float z = Zbuf[tl * 258 + tid] * INV_WSCALE + bias;
            v = v + (z - v) * 0.5f;
            bool s = (v >= 1.0f);
            if (ph == 3 && tl == 31) sOut = s ? 1.f : 0.f;
            v = s ? 0.f : v;
        }
    }
    out[(size_t)n * 256 + tid]           = sOut;   // (64,1,8192) flat
    out[524288u + (size_t)n * 256 + tid] = sOut;   // (64,8192) flat (identical)
}

// ---------------- launcher ----------------
extern "C" void kernel_launch(void* const* d_in, const int* in_sizes, int n_in,
                              void* d_out, int out_size, void* d_ws, size_t ws_size,
                              hipStream_t stream) {
    const float* x      = (const float*)d_in[0];
    const float* conv_w = (const float*)d_in[1];
    const float* conv_b = (const float*)d_in[2];
    const float* gamma  = (const float*)d_in[3];
    const float* beta   = (const float*)d_in[4];
    const float* mean   = (const float*)d_in[5];
    const float* var    = (const float*)d_in[6];
    const float* lin_w  = (const float*)d_in[7];
    const float* lin_b  = (const float*)d_in[8];
    uint8_t* ws = (uint8_t*)d_ws;
    float* out = (float*)d_out;

    hipLaunchKernelGGL(prep_kernel, dim3(257), dim3(256), 0, stream,
                       conv_w, conv_b, gamma, beta, mean, var, lin_w, ws);
    hipLaunchKernelGGL(encoder_kernel, dim3(1024), dim3(256), 0, stream,
                       x, (const float4*)(ws + OFF_C0), (const float4*)(ws + OFF_C1),
                       (u64*)(ws + OFF_SBITS));
    hipLaunchKernelGGL(gemm_scan_kernel, dim3(2048), dim3(256), 0, stream,
                       (const u64*)(ws + OFF_SBITS),
                       (const uint4*)(ws + OFF_WSWZ), lin_b, out);
}